// Round 10
// baseline (26.144 us; speedup 1.0000x reference)
//
#include <hip/hip_runtime.h>

// AdaptiveHyperNN, collapsed + matmul-flattened to dependency depth 2:
//   logit[b,u,v] = feat_u·va + feat_v·vb + Cb, sigmoid at the end.
//   Node 1: PMt = transpose(PM) in bf16 (k-major), PM[0:256]=W1top@W2bot,
//     PM[256:512]=W2top+W1bot@W2bot; rowS=W2bot^T@b1+b2 (fp32);
//     wa/wb = W3@w4t (fp32); c0 scalars.
//   Node 2 (8 blocks/graph): redundant matvec via PMt — wave-uniform Q/AB
//     split, uint2 (4-r) coalesced loads, per-thread register accumulation,
//     LDS partial combine in fixed order; then gather feat -> regs,
//     A/B/sc dots, Cb, sigmoid slice.
// Lessons: R3 cross-block atomics 15-20 µs/round. R4: <16 CUs streaming =
// latency-bound. R5: split deep k-loops over waves. R6: fewer fatter GEMM
// blocks. R7: node slot ≈ 2 µs, replay floor ≈ 18 µs. R8: redundant work
// must be throughput-shaped. R9: never stream with sub-float4 granularity
// (2B loads = 8x instruction count; 128-iter latency-exposed loop ≈ 5 µs).

__device__ __forceinline__ float wred(float v) {
#pragma unroll
  for (int o = 32; o > 0; o >>= 1) v += __shfl_xor(v, o, 64);
  return v;
}
__device__ __forceinline__ float dot4(float4 a, float4 b) {
  return a.x * b.x + a.y * b.y + a.z * b.z + a.w * b.w;
}
__device__ __forceinline__ unsigned short f2bf(float x) {  // RNE, finite data
  union { float f; unsigned int u; } v; v.f = x;
  unsigned int r = (v.u + 0x7fffu + ((v.u >> 16) & 1u)) >> 16;
  return (unsigned short)r;
}
__device__ __forceinline__ float bfhi(unsigned int u) {  // bits already in hi16
  union { unsigned int x; float f; } v; v.x = u; return v.f;
}

// ws layout (float units). PMt = 256x512 bf16 (k-major): 65536 floats.
#define OFF_WA   65536
#define OFF_WB   65792
#define OFF_ROWS 66048   // rowS, 256 fp32
#define OFF_C0   66304   // 8 fp32

// Node 1. blocks 0..63: PM GEMM (8 rows/block, k split over 4 waves),
// LDS-transposed bf16 store into PMt; blocks 64..191: wa/wb wave-per-row;
// block 192: c0 + rowS.
__global__ __launch_bounds__(256) void k1(
    const float* __restrict__ Xs,
    const float* __restrict__ W1, const float* __restrict__ b1,
    const float* __restrict__ W2, const float* __restrict__ b2,
    const float* __restrict__ W3, const float* __restrict__ b3,
    const float* __restrict__ W4, const float* __restrict__ b4,
    float* __restrict__ ws) {
  const int blk = blockIdx.x, tid = threadIdx.x;
  unsigned short* PMt = (unsigned short*)ws;
  const float* W2bot = W2 + 256 * 256;
  __shared__ float w1s[8][256];          // reused as transpose tile
  __shared__ float4 part[8][4][64];

  if (blk < 64) {
    // ---- PM rows r0..r0+7 ----
    const int r0 = blk * 8;
    const int c4 = tid & 63, wv = tid >> 6;
#pragma unroll
    for (int i = 0; i < 8; ++i)
      ((float*)w1s)[i * 256 + tid] = W1[(size_t)r0 * 256 + i * 256 + tid];
    __syncthreads();
    const float4* w2b4 = (const float4*)W2bot;
    float4 acc[8];
#pragma unroll
    for (int i = 0; i < 8; ++i) acc[i] = make_float4(0.f, 0.f, 0.f, 0.f);
    const int kb = wv * 64;
#pragma unroll 4
    for (int i = 0; i < 64; ++i) {
      int k = kb + i;
      float4 w = w2b4[k * 64 + c4];
#pragma unroll
      for (int r = 0; r < 8; ++r) {
        float x = w1s[r][k];
        acc[r].x += x * w.x; acc[r].y += x * w.y;
        acc[r].z += x * w.z; acc[r].w += x * w.w;
      }
    }
#pragma unroll
    for (int r = 0; r < 8; ++r) part[r][wv][c4] = acc[r];
    __syncthreads();   // also: w1s dead, safe to reuse as tile
    // combine partials (fixed order 0+1+2+3) into tile[row][c]
#pragma unroll
    for (int j = 0; j < 2; ++j) {
      int item = tid + j * 256;
      int row = item >> 6, c = item & 63;
      float4 p0 = part[row][0][c], p1 = part[row][1][c];
      float4 p2 = part[row][2][c], p3 = part[row][3][c];
      float4 s = make_float4(p0.x + p1.x + p2.x + p3.x,
                             p0.y + p1.y + p2.y + p3.y,
                             p0.z + p1.z + p2.z + p3.z,
                             p0.w + p1.w + p2.w + p3.w);
      int r = r0 + row;
      if (r >= 256) {
        float4 t = ((const float4*)(W2 + (size_t)(r - 256) * 256))[c];
        s.x += t.x; s.y += t.y; s.z += t.z; s.w += t.w;
      }
      ((float4*)w1s[row])[c] = s;
    }
    __syncthreads();
    // transposed bf16 store: thread c writes PMt[c][r0..r0+7] (16 B)
    if (tid < 256) {
      unsigned int p0 = (unsigned int)f2bf(w1s[0][tid]) |
                        ((unsigned int)f2bf(w1s[1][tid]) << 16);
      unsigned int p1 = (unsigned int)f2bf(w1s[2][tid]) |
                        ((unsigned int)f2bf(w1s[3][tid]) << 16);
      unsigned int p2 = (unsigned int)f2bf(w1s[4][tid]) |
                        ((unsigned int)f2bf(w1s[5][tid]) << 16);
      unsigned int p3 = (unsigned int)f2bf(w1s[6][tid]) |
                        ((unsigned int)f2bf(w1s[7][tid]) << 16);
      uint4 v = make_uint4(p0, p1, p2, p3);
      *((uint4*)(PMt + (size_t)tid * 512 + r0)) = v;
    }
  } else if (blk < 192) {
    // ---- wa/wb = W3 @ w4t, wave per row (fp32) ----
    const int lane = tid & 63, wv = tid >> 6;
    const int t = (blk - 64) * 4 + wv;  // 0..511
    float4 w4a = ((const float4*)W4)[lane];
    float4 rv = ((const float4*)(W3 + (size_t)t * 256))[lane];
    float s = wred(dot4(rv, w4a));
    if (lane == 0) {
      if (t < 256) ws[OFF_WA + t] = s; else ws[OFF_WB + t - 256] = s;
    }
  } else {
    // ---- c0 scalars + rowS = W2bot^T @ b1 + b2 (fp32) ----
    const int lane = tid & 63, wv = tid >> 6;
    float4 w4a = ((const float4*)W4)[lane];
    float4 w4b4 = ((const float4*)W4)[lane + 64];
    float sb3 = wred(dot4(((const float4*)b3)[lane], w4a));
    for (int bi = wv; bi < 8; bi += 4) {
      float xd = wred(dot4(((const float4*)(Xs + (size_t)bi * 256))[lane], w4b4));
      if (lane == 0) ws[OFF_C0 + bi] = b4[0] + sb3 + xd;
    }
    const int c4 = tid & 63, rg = tid >> 6;
    const float4* w2b4 = (const float4*)W2bot;
    float4 acc = make_float4(0.f, 0.f, 0.f, 0.f);
#pragma unroll 8
    for (int i = 0; i < 64; ++i) {
      int k = rg * 64 + i;
      float4 w = w2b4[k * 64 + c4];
      float bv = b1[k];
      acc.x += bv * w.x; acc.y += bv * w.y; acc.z += bv * w.z; acc.w += bv * w.w;
    }
    part[0][rg][c4] = acc;
    __syncthreads();
    if (tid < 64) {
      float4 p0 = part[0][0][tid], p1 = part[0][1][tid];
      float4 p2 = part[0][2][tid], p3 = part[0][3][tid];
      float4 bb = ((const float4*)b2)[tid];
      float4 s = make_float4(p0.x + p1.x + p2.x + p3.x + bb.x,
                             p0.y + p1.y + p2.y + p3.y + bb.y,
                             p0.z + p1.z + p2.z + p3.z + bb.z,
                             p0.w + p1.w + p2.w + p3.w + bb.w);
      ((float4*)(ws + OFF_ROWS))[tid] = s;
    }
  }
}

// Node 2: 8 blocks per graph (64 total), 1024 threads.
// Phase A (redundant, identical in every block):
//   waves 0..7  : qs rows  — wave w = k-slice [32w,32w+32), lane = 4-r group,
//                 uint2 loads (4 bf16 r-values), 4 register accumulators.
//   waves 8..15 : va/vb rows — same shape, 8 accumulators (wa & wb).
//   Partials -> pQ/pA/pB[8][256]; combine in fixed ks order. Wave 12 lane
//   group also computes the lone sAll wred afterwards.
// Phase B: gather feat rows (short-lived regs), A/B/sc wred dots.
// Phase C: Cb, 16-row sigmoid slice.
__global__ __launch_bounds__(1024) void k23(
    const float* __restrict__ api, const int* __restrict__ invoked,
    const float* __restrict__ ws, float* __restrict__ out) {
  const int g = blockIdx.x >> 3, sub = blockIdx.x & 7;
  const int tid = threadIdx.x;
  const int lane = tid & 63, wv = tid >> 6;  // wv 0..15
  const unsigned short* PMt = (const unsigned short*)ws;
  __shared__ float waL[256], wbL[256], swL[256];
  __shared__ alignas(16) float pQ[8][256], pA[8][256], pB[8][256];
  __shared__ alignas(16) float qsL[256], vaL[256], vbL[256];
  __shared__ alignas(16) float Ash[128], Bsh[128], scsh[128];
  __shared__ float CbSh, sAllSh;

  if (tid < 256) {
    float a = ws[OFF_WA + tid], b = ws[OFF_WB + tid];
    waL[tid] = a; wbL[tid] = b; swL[tid] = a + b;
  }
  __syncthreads();

  // ---- phase A: coalesced thread-per-4-outputs matvec ----
  {
    const int ks = wv & 7;          // k-slice, wave-uniform
    const int k0 = ks << 5;
    const int rb = lane << 2;       // 4-r group base (0..252)
    if (wv < 8) {
      // qs rows: PMt[k][rb..rb+3], weight swL[k]
      float a0 = 0.f, a1 = 0.f, a2 = 0.f, a3 = 0.f;
#pragma unroll 8
      for (int i = 0; i < 32; ++i) {
        int k = k0 + i;
        uint2 h = *(const uint2*)(PMt + (size_t)k * 512 + rb);
        float sw = swL[k];
        a0 += bfhi(h.x << 16) * sw;
        a1 += bfhi(h.x & 0xffff0000u) * sw;
        a2 += bfhi(h.y << 16) * sw;
        a3 += bfhi(h.y & 0xffff0000u) * sw;
      }
      *(float4*)&pQ[ks][rb] = make_float4(a0, a1, a2, a3);
    } else {
      // va/vb rows: PMt[k][256+rb ..], weights waL[k], wbL[k]
      float aa0 = 0.f, aa1 = 0.f, aa2 = 0.f, aa3 = 0.f;
      float bb0 = 0.f, bb1 = 0.f, bb2 = 0.f, bb3 = 0.f;
#pragma unroll 8
      for (int i = 0; i < 32; ++i) {
        int k = k0 + i;
        uint2 h = *(const uint2*)(PMt + (size_t)k * 512 + 256 + rb);
        float wA = waL[k], wB = wbL[k];
        float m0 = bfhi(h.x << 16), m1 = bfhi(h.x & 0xffff0000u);
        float m2 = bfhi(h.y << 16), m3 = bfhi(h.y & 0xffff0000u);
        aa0 += m0 * wA; bb0 += m0 * wB;
        aa1 += m1 * wA; bb1 += m1 * wB;
        aa2 += m2 * wA; bb2 += m2 * wB;
        aa3 += m3 * wA; bb3 += m3 * wB;
      }
      *(float4*)&pA[ks][rb] = make_float4(aa0, aa1, aa2, aa3);
      *(float4*)&pB[ks][rb] = make_float4(bb0, bb1, bb2, bb3);
    }
  }
  __syncthreads();
  // combine partials (fixed ks order -> deterministic, identical per block)
  if (tid < 256) {
    float s = pQ[0][tid];
#pragma unroll
    for (int j = 1; j < 8; ++j) s += pQ[j][tid];
    qsL[tid] = s;
  } else if (tid < 512) {
    int r = tid - 256;
    float s = pA[0][r];
#pragma unroll
    for (int j = 1; j < 8; ++j) s += pA[j][r];
    vaL[r] = s;
  } else if (tid < 768) {
    int r = tid - 512;
    float s = pB[0][r];
#pragma unroll
    for (int j = 1; j < 8; ++j) s += pB[j][r];
    vbL[r] = s;
  } else if (wv == 12) {  // sAll = rowS·(wa+wb): the one wred of phase A
    float4 rs = ((const float4*)(ws + OFF_ROWS))[lane];
    int k = lane * 4;
    float s = rs.x * swL[k] + rs.y * swL[k + 1] +
              rs.z * swL[k + 2] + rs.w * swL[k + 3];
    s = wred(s);
    if (lane == 0) sAllSh = s;
  }
  __syncthreads();

  // ---- phase B: gather + A/B/sc dots (identical order in all blocks) ----
  {
    float4 f[8];
    const int ub = wv * 8;
    int idx[8];
#pragma unroll
    for (int i = 0; i < 8; ++i) idx[i] = invoked[(g << 7) + ub + i];
#pragma unroll
    for (int i = 0; i < 8; ++i)
      f[i] = ((const float4*)(api + (size_t)idx[i] * 256))[lane];
    float4 va4 = ((const float4*)vaL)[lane];
    float4 vb4 = ((const float4*)vbL)[lane];
    float4 q4  = ((const float4*)qsL)[lane];
#pragma unroll
    for (int i = 0; i < 8; ++i) {
      float sa = wred(dot4(f[i], va4));
      float sb = wred(dot4(f[i], vb4));
      float sc = wred(dot4(f[i], q4));
      if (lane == 0) { Ash[ub + i] = sa; Bsh[ub + i] = sb; scsh[ub + i] = sc; }
    }
  }
  __syncthreads();
  if (wv == 0) {  // deterministic fixed-order Cb reduction
    float t = scsh[lane] + scsh[lane + 64];
    t = wred(t);
    if (lane == 0) CbSh = t * (1.f / 128.f) + ws[OFF_C0 + g] + sAllSh;
  }
  __syncthreads();

  // ---- phase C: 16-row sigmoid slice ----
  const float Cb = CbSh;
  if (tid < 512) {
    int u = (sub << 4) + (tid >> 5);   // 32 float4 per row
    int v4 = tid & 31;
    float a = Ash[u] + Cb;
    float4 bv = ((const float4*)Bsh)[v4];
    float4 r;
    r.x = 1.f / (1.f + __expf(-(a + bv.x)));
    r.y = 1.f / (1.f + __expf(-(a + bv.y)));
    r.z = 1.f / (1.f + __expf(-(a + bv.z)));
    r.w = 1.f / (1.f + __expf(-(a + bv.w)));
    ((float4*)(out + (g << 14) + (u << 7)))[v4] = r;
  }
}

extern "C" void kernel_launch(void* const* d_in, const int* in_sizes, int n_in,
                              void* d_out, int out_size, void* d_ws, size_t ws_size,
                              hipStream_t stream) {
  const float* Xs  = (const float*)d_in[0];
  const float* api = (const float*)d_in[1];
  const float* W1  = (const float*)d_in[2];
  const float* b1  = (const float*)d_in[3];
  const float* W2  = (const float*)d_in[4];
  const float* b2  = (const float*)d_in[5];
  const float* W3  = (const float*)d_in[6];
  const float* b3  = (const float*)d_in[7];
  const float* W4  = (const float*)d_in[8];
  const float* b4  = (const float*)d_in[9];
  const int* invoked = (const int*)d_in[10];
  float* out = (float*)d_out;
  float* ws = (float*)d_ws;

  hipLaunchKernelGGL(k1, dim3(193), dim3(256), 0, stream,
                     Xs, W1, b1, W2, b2, W3, b3, W4, b4, ws);
  hipLaunchKernelGGL(k23, dim3(64), dim3(1024), 0, stream,
                     api, invoked, ws, out);
}

// Round 11
// 22.846 us; speedup vs baseline: 1.1443x; 1.1443x over previous
//
#include <hip/hip_runtime.h>

// AdaptiveHyperNN, collapsed + matmul-flattened to dependency depth 2:
//   logit[b,u,v] = feat_u·va + feat_v·vb + Cb, sigmoid at the end.
//   Node 1 (independent): PM GEMM (PM[0:256]=W1top@W2bot; PM[256:512]=
//     W2top+W1bot@W2bot; PM[512]=W2bot^T@b1+b2), wa/wb = W3@w4t, c0.
//   Node 2: va/vb = PM[256:]·w{a,b}; qsum = PM[:256]·(wa+wb); cAll.
//   Node 3: per graph (8 blocks each): gather feat from L3-resident api,
//     A/B/sc dots (redundant per block, identical order), Cb, sigmoid slice.
// Final config = Round-7 argmin (23.0 µs measured). Ten-round conclusion:
// wall is ~80% fixed graph-replay overhead (~18-21 µs); node count
// 4/3/2 gave 25.1/23.0/26.1 (non-monotone); body-level rewrites were
// null once each stage was wide + throughput-shaped. Lessons retained:
// R3 cross-block atomics 15-20 µs/round — never. R4: <16 CUs streaming =
// latency-bound (~24 GB/s/CU). R5: split deep k-loops over waves.
// R6: fewer fatter GEMM blocks (B-read is fixed per block). R8: redundant
// work must be throughput-shaped, never wred chains. R9: never stream
// sub-float4 granularity. R10: 2-node redundancy tax ≈ saved slot.

__device__ __forceinline__ float wred(float v) {
#pragma unroll
  for (int o = 32; o > 0; o >>= 1) v += __shfl_xor(v, o, 64);
  return v;
}
__device__ __forceinline__ float dot4(float4 a, float4 b) {
  return a.x * b.x + a.y * b.y + a.z * b.z + a.w * b.w;
}

// ws float offsets
#define OFF_PM   0        // 513*256 = 131328
#define OFF_WA   131328   // 256
#define OFF_WB   131584   // 256
#define OFF_VA   131840   // 256
#define OFF_VB   132096   // 256
#define OFF_QS   132352   // 256
#define OFF_C0   132608   // 8
#define OFF_CALL 132616   // 8   (total ~530 KB)

// Node 1. blocks 0..63: PM GEMM, 8 rows/block, k split over 4 waves;
// blocks 64..191: wa/wb wave-per-row; block 192: c0 + PM[512].
__global__ __launch_bounds__(256) void k1(
    const float* __restrict__ Xs,
    const float* __restrict__ W1, const float* __restrict__ b1,
    const float* __restrict__ W2, const float* __restrict__ b2,
    const float* __restrict__ W3, const float* __restrict__ b3,
    const float* __restrict__ W4, const float* __restrict__ b4,
    float* __restrict__ ws) {
  const int blk = blockIdx.x, tid = threadIdx.x;
  float* PM = ws + OFF_PM;
  const float* W2bot = W2 + 256 * 256;
  __shared__ float w1s[8][256];
  __shared__ float4 part[8][4][64];

  if (blk < 64) {
    // ---- PM rows r0..r0+7 ----
    const int r0 = blk * 8;
    const int c4 = tid & 63, wv = tid >> 6;
#pragma unroll
    for (int i = 0; i < 8; ++i)
      ((float*)w1s)[i * 256 + tid] = W1[(size_t)r0 * 256 + i * 256 + tid];
    __syncthreads();
    const float4* w2b4 = (const float4*)W2bot;
    float4 acc[8];
#pragma unroll
    for (int i = 0; i < 8; ++i) acc[i] = make_float4(0.f, 0.f, 0.f, 0.f);
    const int kb = wv * 64;
#pragma unroll 4
    for (int i = 0; i < 64; ++i) {
      int k = kb + i;
      float4 w = w2b4[k * 64 + c4];
#pragma unroll
      for (int r = 0; r < 8; ++r) {
        float x = w1s[r][k];
        acc[r].x += x * w.x; acc[r].y += x * w.y;
        acc[r].z += x * w.z; acc[r].w += x * w.w;
      }
    }
#pragma unroll
    for (int r = 0; r < 8; ++r) part[r][wv][c4] = acc[r];
    __syncthreads();
    // 512 outputs (row,c4) over 256 threads, 2 each; fixed order 0+1+2+3
#pragma unroll
    for (int j = 0; j < 2; ++j) {
      int item = tid + j * 256;
      int row = item >> 6, c = item & 63;
      float4 p0 = part[row][0][c], p1 = part[row][1][c];
      float4 p2 = part[row][2][c], p3 = part[row][3][c];
      float4 s = make_float4(p0.x + p1.x + p2.x + p3.x,
                             p0.y + p1.y + p2.y + p3.y,
                             p0.z + p1.z + p2.z + p3.z,
                             p0.w + p1.w + p2.w + p3.w);
      int r = r0 + row;
      if (r >= 256) {
        float4 t = ((const float4*)(W2 + (size_t)(r - 256) * 256))[c];
        s.x += t.x; s.y += t.y; s.z += t.z; s.w += t.w;
      }
      ((float4*)(PM + (size_t)r * 256))[c] = s;
    }
  } else if (blk < 192) {
    // ---- wa/wb = W3 @ w4t, wave per row ----
    const int lane = tid & 63, wv = tid >> 6;
    const int t = (blk - 64) * 4 + wv;  // 0..511
    float4 w4a = ((const float4*)W4)[lane];
    float4 rv = ((const float4*)(W3 + (size_t)t * 256))[lane];
    float s = wred(dot4(rv, w4a));
    if (lane == 0) {
      if (t < 256) ws[OFF_WA + t] = s; else ws[OFF_WB + t - 256] = s;
    }
  } else {
    // ---- c0 scalars + PM[512] = W2bot^T @ b1 + b2 ----
    const int lane = tid & 63, wv = tid >> 6;
    float4 w4a = ((const float4*)W4)[lane];
    float4 w4b4 = ((const float4*)W4)[lane + 64];
    float sb3 = wred(dot4(((const float4*)b3)[lane], w4a));
    for (int bi = wv; bi < 8; bi += 4) {
      float xd = wred(dot4(((const float4*)(Xs + (size_t)bi * 256))[lane], w4b4));
      if (lane == 0) ws[OFF_C0 + bi] = b4[0] + sb3 + xd;
    }
    const int c4 = tid & 63, rg = tid >> 6;
    const float4* w2b4 = (const float4*)W2bot;
    float4 acc = make_float4(0.f, 0.f, 0.f, 0.f);
#pragma unroll 8
    for (int i = 0; i < 64; ++i) {
      int k = rg * 64 + i;
      float4 w = w2b4[k * 64 + c4];
      float bv = b1[k];
      acc.x += bv * w.x; acc.y += bv * w.y; acc.z += bv * w.z; acc.w += bv * w.w;
    }
    part[0][rg][c4] = acc;
    __syncthreads();
    if (tid < 64) {
      float4 p0 = part[0][0][tid], p1 = part[0][1][tid];
      float4 p2 = part[0][2][tid], p3 = part[0][3][tid];
      float4 bb = ((const float4*)b2)[tid];
      float4 s = make_float4(p0.x + p1.x + p2.x + p3.x + bb.x,
                             p0.y + p1.y + p2.y + p3.y + bb.y,
                             p0.z + p1.z + p2.z + p3.z + bb.z,
                             p0.w + p1.w + p2.w + p3.w + bb.w);
      ((float4*)(PM + (size_t)512 * 256))[tid] = s;
    }
  }
}

// Node 2: blocks 0..127 wave-per-row dots against PM; block 128: cAll.
__global__ __launch_bounds__(256) void k2(float* __restrict__ ws) {
  const int blk = blockIdx.x, tid = threadIdx.x;
  const int lane = tid & 63, wv = tid >> 6;
  const float* PM = ws + OFF_PM;
  float4 wa4 = ((const float4*)(ws + OFF_WA))[lane];
  float4 wb4 = ((const float4*)(ws + OFF_WB))[lane];
  if (blk < 128) {
    const int t = blk * 4 + wv;  // 0..511, wave-uniform branch
    if (t < 256) {
      float4 rv = ((const float4*)(PM + (size_t)(256 + t) * 256))[lane];
      float sa = wred(dot4(rv, wa4));
      float sb = wred(dot4(rv, wb4));
      if (lane == 0) { ws[OFF_VA + t] = sa; ws[OFF_VB + t] = sb; }
    } else {
      float4 rv = ((const float4*)(PM + (size_t)(t - 256) * 256))[lane];
      float4 s4 = make_float4(wa4.x + wb4.x, wa4.y + wb4.y,
                              wa4.z + wb4.z, wa4.w + wb4.w);
      float s = wred(dot4(rv, s4));
      if (lane == 0) ws[OFF_QS + t - 256] = s;
    }
  } else {
    __shared__ float sAllSh;
    if (wv == 0) {
      float4 rv = ((const float4*)(PM + (size_t)512 * 256))[lane];
      float4 s4 = make_float4(wa4.x + wb4.x, wa4.y + wb4.y,
                              wa4.z + wb4.z, wa4.w + wb4.w);
      float s = wred(dot4(rv, s4));
      if (lane == 0) sAllSh = s;
    }
    __syncthreads();
    if (tid < 8) ws[OFF_CALL + tid] = ws[OFF_C0 + tid] + sAllSh;
  }
}

// Node 3: 8 blocks per graph (64 total), 1024 threads. Each block gathers
// its graph's 128 feat rows (api is L3-resident), computes the full
// A/B/sc dot set (identical order in every block -> identical values),
// then writes its 16-row output slice.
__global__ __launch_bounds__(1024) void k3(
    const float* __restrict__ api, const int* __restrict__ invoked,
    const float* __restrict__ ws, float* __restrict__ out) {
  const int g = blockIdx.x >> 3, sub = blockIdx.x & 7;
  const int tid = threadIdx.x;
  const int lane = tid & 63, wv = tid >> 6;  // wv 0..15
  __shared__ alignas(16) float Ash[128], Bsh[128], scsh[128];
  __shared__ float CbSh;

  // gather 8 rows/wave into regs
  float4 f[8];
  const int ub = wv * 8;
  int idx[8];
#pragma unroll
  for (int i = 0; i < 8; ++i) idx[i] = invoked[(g << 7) + ub + i];
#pragma unroll
  for (int i = 0; i < 8; ++i)
    f[i] = ((const float4*)(api + (size_t)idx[i] * 256))[lane];

  float4 va4 = ((const float4*)(ws + OFF_VA))[lane];
  float4 vb4 = ((const float4*)(ws + OFF_VB))[lane];
  float4 q4  = ((const float4*)(ws + OFF_QS))[lane];
#pragma unroll
  for (int i = 0; i < 8; ++i) {
    float sa = wred(dot4(f[i], va4));
    float sb = wred(dot4(f[i], vb4));
    float sc = wred(dot4(f[i], q4));
    if (lane == 0) { Ash[ub + i] = sa; Bsh[ub + i] = sb; scsh[ub + i] = sc; }
  }
  __syncthreads();
  if (wv == 0) {  // deterministic fixed-order Cb reduction
    float t = scsh[lane] + scsh[lane + 64];
    t = wred(t);
    if (lane == 0) CbSh = t * (1.f / 128.f) + ws[OFF_CALL + g];
  }
  __syncthreads();
  const float Cb = CbSh;
  // this block's slice: u in [sub*16, sub*16+16) -> 16*128 = 512 float4
  if (tid < 512) {
    int u = (sub << 4) + (tid >> 5);   // 32 float4 per row
    int v4 = tid & 31;
    float a = Ash[u] + Cb;
    float4 bv = ((const float4*)Bsh)[v4];
    float4 r;
    r.x = 1.f / (1.f + __expf(-(a + bv.x)));
    r.y = 1.f / (1.f + __expf(-(a + bv.y)));
    r.z = 1.f / (1.f + __expf(-(a + bv.z)));
    r.w = 1.f / (1.f + __expf(-(a + bv.w)));
    ((float4*)(out + (g << 14) + (u << 7)))[v4] = r;
  }
}

extern "C" void kernel_launch(void* const* d_in, const int* in_sizes, int n_in,
                              void* d_out, int out_size, void* d_ws, size_t ws_size,
                              hipStream_t stream) {
  const float* Xs  = (const float*)d_in[0];
  const float* api = (const float*)d_in[1];
  const float* W1  = (const float*)d_in[2];
  const float* b1  = (const float*)d_in[3];
  const float* W2  = (const float*)d_in[4];
  const float* b2  = (const float*)d_in[5];
  const float* W3  = (const float*)d_in[6];
  const float* b3  = (const float*)d_in[7];
  const float* W4  = (const float*)d_in[8];
  const float* b4  = (const float*)d_in[9];
  const int* invoked = (const int*)d_in[10];
  float* out = (float*)d_out;
  float* ws = (float*)d_ws;

  hipLaunchKernelGGL(k1, dim3(193), dim3(256), 0, stream,
                     Xs, W1, b1, W2, b2, W3, b3, W4, b4, ws);
  hipLaunchKernelGGL(k2, dim3(129), dim3(256), 0, stream, ws);
  hipLaunchKernelGGL(k3, dim3(64), dim3(1024), 0, stream,
                     api, invoked, ws, out);
}